// Round 4
// baseline (478.811 us; speedup 1.0000x reference)
//
#include <hip/hip_runtime.h>
#include <hip/hip_bf16.h>

// TransformerBlock fused kernel for MI355X (gfx950) — v4: unpin the allocator.
// Shapes: B=1024, T=128, D=128, H=4, HD=32, FF=512.
// One block per batch element; 512 threads = 8 waves.
// v2.1/v3 history: __launch_bounds__(512,4) empirically pins the allocator to
// 64 arch VGPRs and it SPILLS (~120-200MB scratch traffic) instead of using
// the 128-reg budget 4 waves/EU permits. v1 with (512,2) landed at 100 VGPRs,
// zero spill, with a larger live set than v3's. v4 = v3 structure compiled
// with __launch_bounds__(512,2): allocator free to use ~100-120 regs; runtime
// occupancy is resource-determined, so with VGPR<=128 and LDS=64KiB the HW
// still co-schedules 2 blocks/CU (4 waves/EU).
// Structure (unchanged from v3):
//  - Swapped QK^T: S^T = mfma(K_frag, Q_frag); softmax row in-lane, 2 shuffles.
//  - Per-head Q built in-loop from K-staging hf frags (no persistent Q frags).
//  - Deferred softmax normalization (unnormalized exp packed bf16; 1/sum
//    applied to PV output, redistributed with one shfl per row).
//  - Per-head K_h[128][40] / V_h^T[32][128](swz) staged from hs; per-head Wo
//    partials into f32 x1acc via per-wave 16x40 bounce; LN2 in-register.
//  - XOR-swizzled [128][128] tiles for hs/h2/G; f32 epilogue overlay.
// MFMA 16x16x32 bf16. A-frag: A[m=lane&15][k=quad*8+j]; B-frag:
// B[k=quad*8+j][n=lane&15]; C/D: col=lane&15, row=quad*4+reg (learn_hip m89/m91).

typedef short bf16x8 __attribute__((ext_vector_type(8)));   // 8 bf16 in 4 VGPRs
typedef float f32x4  __attribute__((ext_vector_type(4)));
typedef unsigned short u16;
typedef unsigned int   u32;

#define TT   128
#define DDIM 128
#define FFD  512
#define KPIT 40    // K_h / bounce row pitch in u16 (80 B: 16B-aligned, 2-way banks)

// SCALE * log2(e): softmax done in exp2 domain with Q pre-scaled.
#define QSCALE 0.12751743f

#if defined(__has_builtin)
#if __has_builtin(__builtin_amdgcn_exp2f)
#define EXP2F(x) __builtin_amdgcn_exp2f(x)
#else
#define EXP2F(x) exp2f(x)
#endif
#if __has_builtin(__builtin_amdgcn_rcpf)
#define RCPF(x) __builtin_amdgcn_rcpf(x)
#else
#define RCPF(x) (1.0f / (x))
#endif
#else
#define EXP2F(x) exp2f(x)
#define RCPF(x) (1.0f / (x))
#endif

__device__ __forceinline__ u16 f2b(float f) {
    __hip_bfloat16 h = __float2bfloat16(f);   // RNE
    return __builtin_bit_cast(u16, h);
}
__device__ __forceinline__ u32 pk2(float x, float y) {
    return (u32)f2b(x) | ((u32)f2b(y) << 16);
}
__device__ __forceinline__ bf16x8 ldfrag(const u16* p) {  // LDS, 16B-aligned
    return __builtin_bit_cast(bf16x8, *reinterpret_cast<const uint4*>(p));
}
// Load 8 f32 from global, round to bf16 fragment (16B-aligned base).
__device__ __forceinline__ bf16x8 ldfrag_f32(const float* p) {
    float4 a = *reinterpret_cast<const float4*>(p);
    float4 b = *reinterpret_cast<const float4*>(p + 4);
    bf16x8 r;
    r[0] = (short)f2b(a.x); r[1] = (short)f2b(a.y);
    r[2] = (short)f2b(a.z); r[3] = (short)f2b(a.w);
    r[4] = (short)f2b(b.x); r[5] = (short)f2b(b.y);
    r[6] = (short)f2b(b.z); r[7] = (short)f2b(b.w);
    return r;
}
__device__ __forceinline__ f32x4 mfma16(bf16x8 a, bf16x8 b, f32x4 c) {
    return __builtin_amdgcn_mfma_f32_16x16x32_bf16(a, b, c, 0, 0, 0);
}
// Swizzled [128][128] bf16 tile: byte = row*256 + ((cg ^ (row&7))*16) + (col&7)*2
__device__ __forceinline__ bf16x8 ld_sw(const u16* base, int row, int cg) {
    return ldfrag(base + row * 128 + ((cg ^ (row & 7)) * 8));
}
__device__ __forceinline__ void st_sw(u16* base, int row, int col, u16 v) {
    base[row * 128 + (((col >> 3) ^ (row & 7)) * 8) + (col & 7)] = v;
}

// Cross-quad repack (packed input): pkv[i][d0] = pack(V[row][i*16+quad*4+2*d0],
// V[row][i*16+quad*4+2*d0+1]) (C-layout columns of this lane's row, bf16 pairs);
// output fr[g][j] = bf16(V[row][g*32 + quad*8 + j]) (A/B-frag layout).
// Row (= lane&15) preserved; only quad-dim moves. Derivation: col bits b4..b0;
// src lane quad=(b3,b2), dword=(b4,b1); dst lane quad=(b4,b3), dword=(b2,b1).
__device__ __forceinline__ void quad_collect_pk(const u32 (&pkv)[8][2],
                                                bf16x8 (&fr)[4], int lane) {
    const int srcA = (lane & 15) + ((lane & 16) << 1);  // lq + 32*l4'
    const int srcB = srcA + 16;
    const bool hi = (lane & 32) != 0;                   // l5'
    #pragma unroll
    for (int g = 0; g < 4; g++) {
        u32 D00 = pkv[2*g][0],     D01 = pkv[2*g][1];
        u32 D10 = pkv[2*g + 1][0], D11 = pkv[2*g + 1][1];
        u32 a00 = (u32)__shfl((int)D00, srcA);
        u32 a10 = (u32)__shfl((int)D10, srcA);
        u32 a01 = (u32)__shfl((int)D01, srcA);
        u32 a11 = (u32)__shfl((int)D11, srcA);
        u32 b00 = (u32)__shfl((int)D00, srcB);
        u32 b10 = (u32)__shfl((int)D10, srcB);
        u32 b01 = (u32)__shfl((int)D01, srcB);
        u32 b11 = (u32)__shfl((int)D11, srcB);
        uint4 q;
        q.x = hi ? a10 : a00;
        q.y = hi ? a11 : a01;
        q.z = hi ? b10 : b00;
        q.w = hi ? b11 : b01;
        fr[g] = __builtin_bit_cast(bf16x8, q);
    }
}
// Single-frag variant (one 2-tile group, e.g. one head's 32 columns).
__device__ __forceinline__ bf16x8 quad_collect1(u32 D00, u32 D01, u32 D10, u32 D11,
                                                int lane) {
    const int srcA = (lane & 15) + ((lane & 16) << 1);
    const int srcB = srcA + 16;
    const bool hi = (lane & 32) != 0;
    u32 a00 = (u32)__shfl((int)D00, srcA);
    u32 a10 = (u32)__shfl((int)D10, srcA);
    u32 a01 = (u32)__shfl((int)D01, srcA);
    u32 a11 = (u32)__shfl((int)D11, srcA);
    u32 b00 = (u32)__shfl((int)D00, srcB);
    u32 b10 = (u32)__shfl((int)D10, srcB);
    u32 b01 = (u32)__shfl((int)D01, srcB);
    u32 b11 = (u32)__shfl((int)D11, srcB);
    uint4 q;
    q.x = hi ? a10 : a00;
    q.y = hi ? a11 : a01;
    q.z = hi ? b10 : b00;
    q.w = hi ? b11 : b01;
    return __builtin_bit_cast(bf16x8, q);
}

__global__ __launch_bounds__(512, 2) void tblock_kernel(
    const float* __restrict__ x,
    const float* __restrict__ ln1g, const float* __restrict__ ln1b,
    const float* __restrict__ Wq,   const float* __restrict__ Wk, const float* __restrict__ Wv,
    const float* __restrict__ Wo,   const float* __restrict__ bo,
    const float* __restrict__ ln2g, const float* __restrict__ ln2b,
    const float* __restrict__ W1,   const float* __restrict__ b1,
    const float* __restrict__ W2,   const float* __restrict__ b2,
    float* __restrict__ out)
{
    // 65,536 B total: bufH [128][128] swizzled (hs -> h2);
    // r2: during attn {Kh [128][40], Vth [32][128] swz, bounce 8x[16][40]},
    //     during FF G [128][128] swizzled.
    // Epilogue overlays whole sm as f32[128][128] (x1 bounce).
    __shared__ __align__(16) u16 sm[32768];
    u16* bufH = sm;
    u16* r2   = sm + 16384;
    u16* Kh   = r2;                   // 128*40 = 5120 u16
    u16* Vth  = r2 + 5120;            // 32*128 = 4096 u16
    u16* bnc  = r2 + 5120 + 4096;     // 8*16*40 = 5120 u16

    const int b    = blockIdx.x;
    const int tid  = threadIdx.x;
    const int w    = tid >> 6;     // wave id 0..7 (owns t-rows [w*16, w*16+16))
    const int l    = tid & 63;
    const int lq   = l & 15;
    const int quad = l >> 4;
    const float* xb = x + (size_t)b * (TT * DDIM);

    // ---------------- P0: LN1(x) -> bufH (bf16, swizzled) ----------------
    {
        const int row = tid >> 2, part = tid & 3;
        const float* src = xb + row * DDIM + part * 32;
        float v[32];
        float s = 0.f, s2 = 0.f;
        #pragma unroll
        for (int i = 0; i < 8; i++) {
            float4 u = *reinterpret_cast<const float4*>(src + i * 4);
            v[i * 4 + 0] = u.x; v[i * 4 + 1] = u.y;
            v[i * 4 + 2] = u.z; v[i * 4 + 3] = u.w;
            s  += u.x + u.y + u.z + u.w;
            s2 += u.x * u.x + u.y * u.y + u.z * u.z + u.w * u.w;
        }
        s  += __shfl_xor(s, 1);  s2 += __shfl_xor(s2, 1);
        s  += __shfl_xor(s, 2);  s2 += __shfl_xor(s2, 2);
        float mean = s * (1.f / 128.f);
        float var  = fmaxf(s2 * (1.f / 128.f) - mean * mean, 0.f);
        float rstd = rsqrtf(var + 1e-5f);
        #pragma unroll
        for (int i = 0; i < 4; i++) {
            u32 o4[4];
            #pragma unroll
            for (int j = 0; j < 4; j++) {
                int c = part * 32 + i * 8 + 2 * j;
                float r0 = (v[i * 8 + 2 * j]     - mean) * rstd * ln1g[c]     + ln1b[c];
                float r1 = (v[i * 8 + 2 * j + 1] - mean) * rstd * ln1g[c + 1] + ln1b[c + 1];
                o4[j] = (u32)f2b(r0) | ((u32)f2b(r1) << 16);
            }
            uint4 pkv; pkv.x = o4[0]; pkv.y = o4[1]; pkv.z = o4[2]; pkv.w = o4[3];
            int g = (part * 4 + i) ^ (row & 7);
            *reinterpret_cast<uint4*>(bufH + row * 128 + g * 8) = pkv;
        }
    }
    __syncthreads();

    // x1 residual accumulator: (t = w*16+quad*4+r, d = nt*16+lq), f32.
    f32x4 x1acc[8];
    #pragma unroll
    for (int i = 0; i < 8; i++) x1acc[i] = f32x4{0, 0, 0, 0};

    // ---------------- P1: per-head attention ----------------
    #pragma unroll 1
    for (int h = 0; h < 4; h++) {
        bf16x8 qh;
        {
            bf16x8 hf[4];
            #pragma unroll
            for (int ks = 0; ks < 4; ks++) hf[ks] = ld_sw(bufH, w * 16 + lq, ks * 4 + quad);
            // --- stage K_h: [t][hd] pitch 40 (wave computes own t rows) ---
            #pragma unroll
            for (int nt2 = 0; nt2 < 2; nt2++) {
                f32x4 acc = {0, 0, 0, 0};
                #pragma unroll
                for (int ks = 0; ks < 4; ks++) {
                    bf16x8 bwk = ldfrag_f32(Wk + (h * 32 + nt2 * 16 + lq) * DDIM + ks * 32 + quad * 8);
                    acc = mfma16(hf[ks], bwk, acc);
                }
                #pragma unroll
                for (int r = 0; r < 4; r++)
                    Kh[(w * 16 + quad * 4 + r) * KPIT + nt2 * 16 + lq] = f2b(acc[r]);
            }
            // --- Q_h (pre-scaled) -> register B-frag via quad shuffle ---
            {
                u32 qpk[2][2];
                #pragma unroll
                for (int nt2 = 0; nt2 < 2; nt2++) {
                    f32x4 acc = {0, 0, 0, 0};
                    #pragma unroll
                    for (int ks = 0; ks < 4; ks++) {
                        bf16x8 aw = ldfrag_f32(Wq + (h * 32 + nt2 * 16 + lq) * DDIM + ks * 32 + quad * 8);
                        acc = mfma16(aw, hf[ks], acc);
                    }
                    qpk[nt2][0] = pk2(acc[0] * QSCALE, acc[1] * QSCALE);
                    qpk[nt2][1] = pk2(acc[2] * QSCALE, acc[3] * QSCALE);
                }
                qh = quad_collect1(qpk[0][0], qpk[0][1], qpk[1][0], qpk[1][1], l);
            }
            // --- stage V_h^T: [o32][t] swizzled (waves split o-halves x t-pairs) ---
            {
                bf16x8 af[4];
                #pragma unroll
                for (int ks = 0; ks < 4; ks++)
                    af[ks] = ldfrag_f32(Wv + (h * 32 + (w >> 2) * 16 + lq) * DDIM + ks * 32 + quad * 8);
                #pragma unroll
                for (int j2 = 0; j2 < 2; j2++) {
                    int nt = 2 * (w & 3) + j2;
                    f32x4 acc = {0, 0, 0, 0};
                    #pragma unroll
                    for (int ks = 0; ks < 4; ks++) {
                        bf16x8 bh = ld_sw(bufH, nt * 16 + lq, ks * 4 + quad);
                        acc = mfma16(af[ks], bh, acc);
                    }
                    #pragma unroll
                    for (int r = 0; r < 4; r++)
                        st_sw(Vth, (w >> 2) * 16 + quad * 4 + r, nt * 16 + lq, f2b(acc[r]));
                }
            }
        }
        __syncthreads();

        // --- S^T = mfma(K_frag, Q_frag): p[ns][r] = S[t=w16+lq][s=ns*16+quad*4+r] ---
        float p[8][4];
        #pragma unroll
        for (int ns = 0; ns < 8; ns++) {
            bf16x8 a = ldfrag(Kh + (ns * 16 + lq) * KPIT + quad * 8);
            f32x4 s4 = mfma16(a, qh, f32x4{0, 0, 0, 0});
            #pragma unroll
            for (int r = 0; r < 4; r++) p[ns][r] = s4[r];
        }
        // --- softmax, deferred normalization (exp2 domain; Q pre-scaled) ---
        const int trow = w * 16 + lq;
        float mx = -3.0e38f;
        #pragma unroll
        for (int ns = 0; ns < 8; ns++) {
            #pragma unroll
            for (int r = 0; r < 4; r++) {
                int sidx = ns * 16 + quad * 4 + r;
                mx = (sidx <= trow) ? fmaxf(mx, p[ns][r]) : mx;
            }
        }
        mx = fmaxf(mx, __shfl_xor(mx, 16));
        mx = fmaxf(mx, __shfl_xor(mx, 32));
        float sum = 0.f;
        u32 ppk[8][2];   // unnormalized exp, packed bf16 pairs
        #pragma unroll
        for (int ns = 0; ns < 8; ns++) {
            float e[4];
            #pragma unroll
            for (int r = 0; r < 4; r++) {
                int sidx = ns * 16 + quad * 4 + r;
                e[r] = (sidx <= trow) ? EXP2F(p[ns][r] - mx) : 0.f;
                sum += e[r];
            }
            ppk[ns][0] = pk2(e[0], e[1]);
            ppk[ns][1] = pk2(e[2], e[3]);
        }
        sum += __shfl_xor(sum, 16);
        sum += __shfl_xor(sum, 32);
        float inv = RCPF(sum);   // sum >= 1 (max lane contributes exp2(0)=1)

        // --- P -> A-frags in-register; attn_h = (P @ V_h) * inv ---
        bf16x8 pfr[4];
        quad_collect_pk(ppk, pfr, l);
        f32x4 av0 = {0, 0, 0, 0}, av1 = {0, 0, 0, 0};
        #pragma unroll
        for (int ks = 0; ks < 4; ks++) {
            int g8 = ((ks * 4 + quad) ^ (lq & 7)) * 8;
            av0 = mfma16(pfr[ks], ldfrag(Vth + lq * 128 + g8), av0);
            av1 = mfma16(pfr[ks], ldfrag(Vth + (16 + lq) * 128 + g8), av1);
        }
        #pragma unroll
        for (int r = 0; r < 4; r++) {
            // inv lives at lane layout t=w16+lq; av rows are t=w16+quad*4+r.
            float invr = __shfl(inv, quad * 4 + r);
            av0[r] *= invr; av1[r] *= invr;
        }
        // --- per-wave bounce (C-layout -> A-frag) + Wo_h partial into x1acc ---
        u16* bw_ = bnc + w * (16 * KPIT);
        #pragma unroll
        for (int r = 0; r < 4; r++) {
            bw_[(quad * 4 + r) * KPIT + lq]      = f2b(av0[r]);
            bw_[(quad * 4 + r) * KPIT + 16 + lq] = f2b(av1[r]);
        }
        asm volatile("s_waitcnt lgkmcnt(0)" ::: "memory");   // intra-wave LDS RAW
        __builtin_amdgcn_sched_barrier(0);
        bf16x8 pa = ldfrag(bw_ + lq * KPIT + quad * 8);
        #pragma unroll
        for (int nt = 0; nt < 8; nt++) {
            bf16x8 wo = ldfrag_f32(Wo + (nt * 16 + lq) * DDIM + h * 32 + quad * 8);
            x1acc[nt] = mfma16(pa, wo, x1acc[nt]);
        }
        __syncthreads();   // Kh/Vth consumed; next head may overwrite
    }

    // ---------------- P3: x1 = x + attn@Wo^T + bo (in regs) ----------------
    #pragma unroll
    for (int nt = 0; nt < 8; nt++) {
        float bov = bo[nt * 16 + lq];
        #pragma unroll
        for (int r = 0; r < 4; r++)
            x1acc[nt][r] += xb[(w * 16 + quad * 4 + r) * DDIM + nt * 16 + lq] + bov;
    }

    // ---------------- P4: LN2 in-register -> h2 into bufH ----------------
    {
        float s[4] = {0, 0, 0, 0}, s2[4] = {0, 0, 0, 0};
        #pragma unroll
        for (int nt = 0; nt < 8; nt++) {
            #pragma unroll
            for (int r = 0; r < 4; r++) {
                float v = x1acc[nt][r];
                s[r] += v; s2[r] += v * v;
            }
        }
        float mean_[4], rstd_[4];
        #pragma unroll
        for (int r = 0; r < 4; r++) {
            #pragma unroll
            for (int m_ = 1; m_ <= 8; m_ <<= 1) {
                s[r]  += __shfl_xor(s[r],  m_);
                s2[r] += __shfl_xor(s2[r], m_);
            }
            mean_[r] = s[r] * (1.f / 128.f);
            float var = fmaxf(s2[r] * (1.f / 128.f) - mean_[r] * mean_[r], 0.f);
            rstd_[r] = rsqrtf(var + 1e-5f);
        }
        #pragma unroll
        for (int nt = 0; nt < 8; nt++) {
            int d = nt * 16 + lq;
            float gg = ln2g[d], bb = ln2b[d];
            #pragma unroll
            for (int r = 0; r < 4; r++) {
                int t2 = w * 16 + quad * 4 + r;
                st_sw(bufH, t2, d, f2b((x1acc[nt][r] - mean_[r]) * rstd_[r] * gg + bb));
            }
        }
    }
    __syncthreads();

    // ---------------- P5: FF, register accumulation over f-chunks ----------------
    f32x4 oacc[8];
    #pragma unroll
    for (int i = 0; i < 8; i++) oacc[i] = f32x4{0, 0, 0, 0};

    #pragma unroll 1
    for (int fc = 0; fc < 4; fc++) {
        const int fbase = fc * 128;
        // G = relu(h2 @ W1c^T + b1) -> r2 (swizzled)
        bf16x8 wf1[4];
        #pragma unroll
        for (int ks = 0; ks < 4; ks++)
            wf1[ks] = ldfrag_f32(W1 + (fbase + w * 16 + lq) * DDIM + ks * 32 + quad * 8);
        const float b1v = b1[fbase + w * 16 + lq];
        #pragma unroll
        for (int m = 0; m < 8; m++) {
            f32x4 acc = {0, 0, 0, 0};
            #pragma unroll
            for (int ks = 0; ks < 4; ks++)
                acc = mfma16(ld_sw(bufH, m * 16 + lq, ks * 4 + quad), wf1[ks], acc);
            #pragma unroll
            for (int r = 0; r < 4; r++) {
                int t2 = m * 16 + quad * 4 + r;
                float gv = acc[r] + b1v;
                gv = gv > 0.f ? gv : 0.f;
                st_sw(r2, t2, w * 16 + lq, f2b(gv));
            }
        }
        __syncthreads();
        // oacc += G @ W2c^T  (wave owns d-cols w*16..)
        bf16x8 wf2[4];
        #pragma unroll
        for (int ks = 0; ks < 4; ks++)
            wf2[ks] = ldfrag_f32(W2 + (w * 16 + lq) * FFD + fbase + ks * 32 + quad * 8);
        #pragma unroll
        for (int m = 0; m < 8; m++) {
            #pragma unroll
            for (int ks = 0; ks < 4; ks++)
                oacc[m] = mfma16(ld_sw(r2, m * 16 + lq, ks * 4 + quad), wf2[ks], oacc[m]);
        }
        __syncthreads();
    }

    // ---------------- P6: x1 layout bounce (f32 LDS overlay) + store ----------------
    float* x1f = reinterpret_cast<float*>(sm);   // h2 and G are dead
    #pragma unroll
    for (int nt = 0; nt < 8; nt++)
        #pragma unroll
        for (int r = 0; r < 4; r++)
            x1f[(w * 16 + quad * 4 + r) * 128 + nt * 16 + lq] = x1acc[nt][r];
    __syncthreads();
    {
        const float b2v = b2[w * 16 + lq];
        float* ob = out + (size_t)b * (TT * DDIM);
        #pragma unroll
        for (int m = 0; m < 8; m++) {
            #pragma unroll
            for (int r = 0; r < 4; r++) {
                int t2 = m * 16 + quad * 4 + r;
                ob[t2 * DDIM + w * 16 + lq] = oacc[m][r] + x1f[t2 * 128 + w * 16 + lq] + b2v;
            }
        }
    }
}

extern "C" void kernel_launch(void* const* d_in, const int* in_sizes, int n_in,
                              void* d_out, int out_size, void* d_ws, size_t ws_size,
                              hipStream_t stream) {
    const float* x    = (const float*)d_in[0];
    const float* ln1g = (const float*)d_in[1];
    const float* ln1b = (const float*)d_in[2];
    const float* Wq   = (const float*)d_in[3];
    const float* Wk   = (const float*)d_in[4];
    const float* Wv   = (const float*)d_in[5];
    const float* Wo   = (const float*)d_in[6];
    const float* bo   = (const float*)d_in[7];
    const float* ln2g = (const float*)d_in[8];
    const float* ln2b = (const float*)d_in[9];
    const float* W1   = (const float*)d_in[10];
    const float* b1   = (const float*)d_in[11];
    const float* W2   = (const float*)d_in[12];
    const float* b2   = (const float*)d_in[13];
    float* out = (float*)d_out;

    const int nblocks = in_sizes[0] / (TT * DDIM);   // B = 1024
    tblock_kernel<<<dim3(nblocks), dim3(512), 0, stream>>>(
        x, ln1g, ln1b, Wq, Wk, Wv, Wo, bo, ln2g, ln2b, W1, b1, W2, b2, out);
}

// Round 5
// 319.063 us; speedup vs baseline: 1.5007x; 1.5007x over previous
//
#include <hip/hip_runtime.h>
#include <hip/hip_bf16.h>

// TransformerBlock fused kernel for MI355X (gfx950) — v5: v1 + barrier surgery.
// Shapes: B=1024, T=128, D=128, H=4, HD=32, FF=512.
// One block per batch element; 512 threads = 8 waves. LDS 139,264 B (1 block/CU).
//
// v2-v4 lesson: occupancy restructures (64KB LDS, per-head staging, shuffle
// repacks) were 1.65x slower per block at equal occupancy; reverted to v1's
// proven structure (234 us) and instead removed its FALSE synchronization:
//  - Head loop: bufB (Q->attn) and bufA (P) are row-partitioned PER WAVE
//    (rows w*16..w*16+15); K (bufC) and Vt (bufD) are read-only after P1.
//    Both per-head __syncthreads() deleted (8 barriers). The only real dep is
//    each wave's own P-store -> PV-load: same-wave s_waitcnt lgkmcnt(0) +
//    sched_barrier(0) (compiler may hoist MFMA past inline-asm waitcnt).
//    The 4-head stretch now runs as 8 independent wave streams per CU.
//  - FF: G ping-pongs between bufA and bufB (both dead after P3) -> the
//    read->next-write WAR barrier per chunk deleted (4 barriers).
//  Barriers: 21 -> 9. Math/layouts identical to v1.
// MFMA 16x16x32 bf16. A-frag: A[m=lane&15][k=quad*8+j]; B-frag:
// B[k=quad*8+j][n=lane&15]; C/D: col=lane&15, row=quad*4+reg (learn_hip m89/m91).

typedef short bf16x8 __attribute__((ext_vector_type(8)));   // 8 bf16 in 4 VGPRs
typedef float f32x4  __attribute__((ext_vector_type(4)));
typedef unsigned short u16;
typedef unsigned int   u32;

#define TT   128
#define DDIM 128
#define FFD  512
#define PIT  136   // LDS row pitch (bf16): 272 B = 17*16 -> rows 16B-aligned; 4-bank stride -> 2-way (free)

__device__ __forceinline__ u16 f2b(float f) {
    __hip_bfloat16 h = __float2bfloat16(f);   // RNE
    return __builtin_bit_cast(u16, h);
}
__device__ __forceinline__ bf16x8 ldfrag(const u16* p) {  // LDS, 16B-aligned
    return __builtin_bit_cast(bf16x8, *reinterpret_cast<const uint4*>(p));
}
// Load 8 f32 from global, round to bf16 fragment (16B-aligned base).
__device__ __forceinline__ bf16x8 ldfrag_f32(const float* p) {
    float4 a = *reinterpret_cast<const float4*>(p);
    float4 b = *reinterpret_cast<const float4*>(p + 4);
    bf16x8 r;
    r[0] = (short)f2b(a.x); r[1] = (short)f2b(a.y);
    r[2] = (short)f2b(a.z); r[3] = (short)f2b(a.w);
    r[4] = (short)f2b(b.x); r[5] = (short)f2b(b.y);
    r[6] = (short)f2b(b.z); r[7] = (short)f2b(b.w);
    return r;
}
__device__ __forceinline__ f32x4 mfma16(bf16x8 a, bf16x8 b, f32x4 c) {
    return __builtin_amdgcn_mfma_f32_16x16x32_bf16(a, b, c, 0, 0, 0);
}

__global__ __launch_bounds__(512, 2) void tblock_kernel(
    const float* __restrict__ x,
    const float* __restrict__ ln1g, const float* __restrict__ ln1b,
    const float* __restrict__ Wq,   const float* __restrict__ Wk, const float* __restrict__ Wv,
    const float* __restrict__ Wo,   const float* __restrict__ bo,
    const float* __restrict__ ln2g, const float* __restrict__ ln2b,
    const float* __restrict__ W1,   const float* __restrict__ b1,
    const float* __restrict__ W2,   const float* __restrict__ b2,
    float* __restrict__ out)
{
    __shared__ __align__(16) u16 sm[4 * TT * PIT];
    u16* bufA = sm;                   // hs(LN1) -> P (per-wave rows) -> G (fc even)
    u16* bufB = sm + 1 * TT * PIT;    // Q -> attn (per-wave rows) -> G (fc odd)
    u16* bufC = sm + 2 * TT * PIT;    // K -> x1 (post-attn residual, bf16 for LN2)
    u16* bufD = sm + 3 * TT * PIT;    // Vt (V transposed) -> h2 (LN2)

    const int b    = blockIdx.x;
    const int tid  = threadIdx.x;
    const int w    = tid >> 6;     // wave id 0..7
    const int l    = tid & 63;
    const int lq   = l & 15;
    const int quad = l >> 4;
    const float* xb = x + (size_t)b * (TT * DDIM);

    // ---------------- P0: LN1(x) -> bufA (bf16) ----------------
    {
        const int row = tid >> 2, part = tid & 3;
        const float* src = xb + row * DDIM + part * 32;
        float v[32];
        float s = 0.f, s2 = 0.f;
        #pragma unroll
        for (int i = 0; i < 8; i++) {
            float4 u = *reinterpret_cast<const float4*>(src + i * 4);
            v[i * 4 + 0] = u.x; v[i * 4 + 1] = u.y;
            v[i * 4 + 2] = u.z; v[i * 4 + 3] = u.w;
            s  += u.x + u.y + u.z + u.w;
            s2 += u.x * u.x + u.y * u.y + u.z * u.z + u.w * u.w;
        }
        s  += __shfl_xor(s, 1);  s2 += __shfl_xor(s2, 1);
        s  += __shfl_xor(s, 2);  s2 += __shfl_xor(s2, 2);
        float mean = s * (1.f / 128.f);
        float var  = fmaxf(s2 * (1.f / 128.f) - mean * mean, 0.f);
        float rstd = rsqrtf(var + 1e-5f);
        u16* dst = bufA + row * PIT + part * 32;
        #pragma unroll
        for (int i = 0; i < 4; i++) {
            u32 o4[4];
            #pragma unroll
            for (int j = 0; j < 4; j++) {
                int c = part * 32 + i * 8 + 2 * j;
                float r0 = (v[i * 8 + 2 * j]     - mean) * rstd * ln1g[c]     + ln1b[c];
                float r1 = (v[i * 8 + 2 * j + 1] - mean) * rstd * ln1g[c + 1] + ln1b[c + 1];
                o4[j] = (u32)f2b(r0) | ((u32)f2b(r1) << 16);
            }
            uint4 pk; pk.x = o4[0]; pk.y = o4[1]; pk.z = o4[2]; pk.w = o4[3];
            *reinterpret_cast<uint4*>(dst + i * 8) = pk;
        }
    }
    __syncthreads();

    // ---------------- P1: Q -> bufB, K -> bufC, Vt -> bufD ----------------
    {
        // Q,K: waves over N (out-cols); weights loaded once per block total.
        bf16x8 bq[4], bk[4];
        #pragma unroll
        for (int ks = 0; ks < 4; ks++) {
            bq[ks] = ldfrag_f32(Wq + (w * 16 + lq) * DDIM + ks * 32 + quad * 8);
            bk[ks] = ldfrag_f32(Wk + (w * 16 + lq) * DDIM + ks * 32 + quad * 8);
        }
        #pragma unroll
        for (int m = 0; m < 8; m++) {
            f32x4 accq = {0, 0, 0, 0}, acck = {0, 0, 0, 0};
            #pragma unroll
            for (int ks = 0; ks < 4; ks++) {
                bf16x8 a = ldfrag(bufA + (m * 16 + lq) * PIT + ks * 32 + quad * 8);
                accq = mfma16(a, bq[ks], accq);
                acck = mfma16(a, bk[ks], acck);
            }
            #pragma unroll
            for (int r = 0; r < 4; r++) {
                int t = m * 16 + quad * 4 + r;
                bufB[t * PIT + w * 16 + lq] = f2b(accq[r]);
                bufC[t * PIT + w * 16 + lq] = f2b(acck[r]);
            }
        }
        // Vt = Wv @ hs^T : waves over M (o-rows). A = Wv rows, B = hs rows.
        bf16x8 av[4];
        #pragma unroll
        for (int ks = 0; ks < 4; ks++)
            av[ks] = ldfrag_f32(Wv + (w * 16 + lq) * DDIM + ks * 32 + quad * 8);
        #pragma unroll
        for (int n = 0; n < 8; n++) {
            f32x4 acc = {0, 0, 0, 0};
            #pragma unroll
            for (int ks = 0; ks < 4; ks++) {
                bf16x8 bh = ldfrag(bufA + (n * 16 + lq) * PIT + ks * 32 + quad * 8);
                acc = mfma16(av[ks], bh, acc);
            }
            #pragma unroll
            for (int r = 0; r < 4; r++) {
                int o = w * 16 + quad * 4 + r;
                bufD[o * PIT + n * 16 + lq] = f2b(acc[r]);
            }
        }
    }
    __syncthreads();

    // ---------------- P2: attention, head by head — NO inter-wave barriers ----
    // bufA (P) and bufB (Q/attn) rows [w*16, w*16+16) are private to wave w;
    // bufC (K) and bufD (Vt) are read-only here. Each wave proceeds freely.
    const float SCALE = 0.08838834764831845f;  // 128^-0.5 (full embed dim, per reference)
    #pragma unroll 1
    for (int h = 0; h < 4; h++) {
        // S = Q_h @ K_h^T ; wave w owns rows [w*16, w*16+16)
        bf16x8 aq = ldfrag(bufB + (w * 16 + lq) * PIT + h * 32 + quad * 8);
        float p[8][4];
        #pragma unroll
        for (int n = 0; n < 8; n++) {
            bf16x8 bk = ldfrag(bufC + (n * 16 + lq) * PIT + h * 32 + quad * 8);
            f32x4 s4 = {0, 0, 0, 0};
            s4 = mfma16(aq, bk, s4);
            #pragma unroll
            for (int r = 0; r < 4; r++) p[n][r] = s4[r];
        }
        // causal mask + softmax; masked entries never go through expf
        #pragma unroll
        for (int r = 0; r < 4; r++) {
            int t = w * 16 + quad * 4 + r;
            float mx = -3.0e38f;
            #pragma unroll
            for (int n = 0; n < 8; n++) {
                int sc = n * 16 + lq;
                float val = p[n][r] * SCALE;
                p[n][r] = val;
                mx = (sc <= t) ? fmaxf(mx, val) : mx;
            }
            mx = fmaxf(mx, __shfl_xor(mx, 1));
            mx = fmaxf(mx, __shfl_xor(mx, 2));
            mx = fmaxf(mx, __shfl_xor(mx, 4));
            mx = fmaxf(mx, __shfl_xor(mx, 8));
            float sum = 0.f;
            #pragma unroll
            for (int n = 0; n < 8; n++) {
                int sc = n * 16 + lq;
                float e = (sc <= t) ? __expf(p[n][r] - mx) : 0.f;
                p[n][r] = e; sum += e;
            }
            sum += __shfl_xor(sum, 1);
            sum += __shfl_xor(sum, 2);
            sum += __shfl_xor(sum, 4);
            sum += __shfl_xor(sum, 8);
            float inv = 1.f / sum;    // sum >= 1 (max lane contributes exp(0)=1)
            #pragma unroll
            for (int n = 0; n < 8; n++)
                bufA[t * PIT + n * 16 + lq] = f2b(p[n][r] * inv);
        }
        // Own P rows fully written by this wave; wait for own LDS stores, then
        // keep the compiler from hoisting the dependent reads/MFMAs above it.
        asm volatile("s_waitcnt lgkmcnt(0)" ::: "memory");
        __builtin_amdgcn_sched_barrier(0);
        // attn_h = P @ V_h  (B-frags from transposed V -> contiguous)
        f32x4 o0 = {0, 0, 0, 0}, o1 = {0, 0, 0, 0};
        #pragma unroll
        for (int ks = 0; ks < 4; ks++) {
            bf16x8 ap  = ldfrag(bufA + (w * 16 + lq) * PIT + ks * 32 + quad * 8);
            bf16x8 bv0 = ldfrag(bufD + (h * 32 + lq) * PIT + ks * 32 + quad * 8);
            bf16x8 bv1 = ldfrag(bufD + (h * 32 + 16 + lq) * PIT + ks * 32 + quad * 8);
            o0 = mfma16(ap, bv0, o0);
            o1 = mfma16(ap, bv1, o1);
        }
        // overwrite Q_h columns with attn_h (wave-local rows; Q_h fully consumed)
        #pragma unroll
        for (int r = 0; r < 4; r++) {
            int t = w * 16 + quad * 4 + r;
            bufB[t * PIT + h * 32 + lq]      = f2b(o0[r]);
            bufB[t * PIT + h * 32 + 16 + lq] = f2b(o1[r]);
        }
    }
    __syncthreads();   // attn concat complete across all waves

    // ---------------- P3: x1 = x + attn @ Wo^T + bo -> regs (f32) + bufC (bf16) ----------------
    float x1res[8][4];   // f32 residual kept in registers for P6
    const int dcol = w * 16 + lq;
    {
        bf16x8 bw[4];
        #pragma unroll
        for (int ks = 0; ks < 4; ks++)
            bw[ks] = ldfrag_f32(Wo + (w * 16 + lq) * DDIM + ks * 32 + quad * 8);
        const float bov = bo[dcol];
        #pragma unroll
        for (int m = 0; m < 8; m++) {
            f32x4 acc = {0, 0, 0, 0};
            #pragma unroll
            for (int ks = 0; ks < 4; ks++) {
                bf16x8 a = ldfrag(bufB + (m * 16 + lq) * PIT + ks * 32 + quad * 8);
                acc = mfma16(a, bw[ks], acc);
            }
            #pragma unroll
            for (int r = 0; r < 4; r++) {
                int t = m * 16 + quad * 4 + r;
                float xv = xb[t * DDIM + dcol];
                float x1 = acc[r] + xv + bov;
                x1res[m][r] = x1;
                bufC[t * PIT + dcol] = f2b(x1);
            }
        }
    }
    __syncthreads();

    // ---------------- P4: LN2(x1) -> bufD (bf16) ----------------
    {
        const int row = tid >> 2, part = tid & 3;
        const u16* src = bufC + row * PIT + part * 32;
        float v[32];
        float s = 0.f, s2 = 0.f;
        #pragma unroll
        for (int i = 0; i < 4; i++) {
            uint4 u = *reinterpret_cast<const uint4*>(src + i * 8);
            u32 arr[4] = {u.x, u.y, u.z, u.w};
            #pragma unroll
            for (int j = 0; j < 4; j++) {
                float f0 = __uint_as_float((arr[j] & 0xffffu) << 16);
                float f1 = __uint_as_float(arr[j] & 0xffff0000u);
                v[i * 8 + 2 * j] = f0; v[i * 8 + 2 * j + 1] = f1;
                s += f0 + f1; s2 += f0 * f0 + f1 * f1;
            }
        }
        s  += __shfl_xor(s, 1);  s2 += __shfl_xor(s2, 1);
        s  += __shfl_xor(s, 2);  s2 += __shfl_xor(s2, 2);
        float mean = s * (1.f / 128.f);
        float var  = fmaxf(s2 * (1.f / 128.f) - mean * mean, 0.f);
        float rstd = rsqrtf(var + 1e-5f);
        u16* dst = bufD + row * PIT + part * 32;
        #pragma unroll
        for (int i = 0; i < 4; i++) {
            u32 o4[4];
            #pragma unroll
            for (int j = 0; j < 4; j++) {
                int c = part * 32 + i * 8 + 2 * j;
                float r0 = (v[i * 8 + 2 * j]     - mean) * rstd * ln2g[c]     + ln2b[c];
                float r1 = (v[i * 8 + 2 * j + 1] - mean) * rstd * ln2g[c + 1] + ln2b[c + 1];
                o4[j] = (u32)f2b(r0) | ((u32)f2b(r1) << 16);
            }
            uint4 pk; pk.x = o4[0]; pk.y = o4[1]; pk.z = o4[2]; pk.w = o4[3];
            *reinterpret_cast<uint4*>(dst + i * 8) = pk;
        }
    }
    __syncthreads();

    // ---------------- P5: FF with register accumulation; G ping-pongs A/B ----
    f32x4 oacc[8];
    #pragma unroll
    for (int m = 0; m < 8; m++) oacc[m] = f32x4{0, 0, 0, 0};

    #pragma unroll 1
    for (int fc = 0; fc < 4; fc++) {
        const int fbase = fc * 128;
        u16* gbuf = (fc & 1) ? bufB : bufA;   // both dead after P3; WAR-free swap
        // G = relu(h2 @ W1c^T + b1) -> gbuf
        bf16x8 wf1[4];
        #pragma unroll
        for (int ks = 0; ks < 4; ks++)
            wf1[ks] = ldfrag_f32(W1 + (fbase + w * 16 + lq) * DDIM + ks * 32 + quad * 8);
        const float b1v = b1[fbase + w * 16 + lq];
        #pragma unroll
        for (int m = 0; m < 8; m++) {
            f32x4 acc = {0, 0, 0, 0};
            #pragma unroll
            for (int ks = 0; ks < 4; ks++) {
                bf16x8 a = ldfrag(bufD + (m * 16 + lq) * PIT + ks * 32 + quad * 8);
                acc = mfma16(a, wf1[ks], acc);
            }
            #pragma unroll
            for (int r = 0; r < 4; r++) {
                int t = m * 16 + quad * 4 + r;
                float g = acc[r] + b1v;
                g = g > 0.f ? g : 0.f;
                gbuf[t * PIT + w * 16 + lq] = f2b(g);
            }
        }
        __syncthreads();   // G_fc complete (cross-wave read follows)
        // oacc += G @ W2c^T
        bf16x8 wf2[4];
        #pragma unroll
        for (int ks = 0; ks < 4; ks++)
            wf2[ks] = ldfrag_f32(W2 + (w * 16 + lq) * FFD + fbase + ks * 32 + quad * 8);
        #pragma unroll
        for (int m = 0; m < 8; m++) {
            #pragma unroll
            for (int ks = 0; ks < 4; ks++) {
                bf16x8 a = ldfrag(gbuf + (m * 16 + lq) * PIT + ks * 32 + quad * 8);
                oacc[m] = mfma16(a, wf2[ks], oacc[m]);
            }
        }
        // no trailing barrier: next fc writes the OTHER buffer
    }

    // ---------------- P6: out = x1(f32 regs) + ff + b2 -> FLOAT32 ----------------
    {
        const float b2v = b2[dcol];
        float* ob = out + (size_t)b * (TT * DDIM);
        #pragma unroll
        for (int m = 0; m < 8; m++) {
            #pragma unroll
            for (int r = 0; r < 4; r++) {
                int t = m * 16 + quad * 4 + r;
                ob[t * DDIM + dcol] = oacc[m][r] + x1res[m][r] + b2v;
            }
        }
    }
}

extern "C" void kernel_launch(void* const* d_in, const int* in_sizes, int n_in,
                              void* d_out, int out_size, void* d_ws, size_t ws_size,
                              hipStream_t stream) {
    const float* x    = (const float*)d_in[0];
    const float* ln1g = (const float*)d_in[1];
    const float* ln1b = (const float*)d_in[2];
    const float* Wq   = (const float*)d_in[3];
    const float* Wk   = (const float*)d_in[4];
    const float* Wv   = (const float*)d_in[5];
    const float* Wo   = (const float*)d_in[6];
    const float* bo   = (const float*)d_in[7];
    const float* ln2g = (const float*)d_in[8];
    const float* ln2b = (const float*)d_in[9];
    const float* W1   = (const float*)d_in[10];
    const float* b1   = (const float*)d_in[11];
    const float* W2   = (const float*)d_in[12];
    const float* b2   = (const float*)d_in[13];
    float* out = (float*)d_out;

    const int nblocks = in_sizes[0] / (TT * DDIM);   // B = 1024
    tblock_kernel<<<dim3(nblocks), dim3(512), 0, stream>>>(
        x, ln1g, ln1b, Wq, Wk, Wv, Wo, bo, ln2g, ln2b, W1, b1, W2, b2, out);
}

// Round 7
// 312.788 us; speedup vs baseline: 1.5308x; 1.0201x over previous
//
#include <hip/hip_runtime.h>
#include <hip/hip_bf16.h>

// TransformerBlock fused kernel for MI355X (gfx950) — v6.1: transposed GEMMs,
// packed b64 LDS stores, quarter-row softmax with cross-quad reduce.
// Shapes: B=1024, T=128, D=128, H=4, HD=32, FF=512.
// One block per batch element; 512 threads = 8 waves. LDS 139,264 B (1 block/CU).
//
// v6 NaN post-mortem: swapped QK^T gives lane (lq,quad) only the QUARTER of
// score row trow=w*16+lq at s = n*16+quad*4+r; full row spans the 4 lanes with
// equal lq. v6's "lane-local" softmax reduced over the quarter -> masked-out
// quads got sum=0 -> inv=inf -> NaN. v6.1 restores the 2 cross-quad butterfly
// shuffles (xor 16, 32) for mx and sum (4 shuffles/head vs v5's 32). inv is
// then full-row and applies to PV output without redistribution (PV output
// rows are n=lq = same trow).
// All v6 layout changes retained:
//  - P1 Q/K swapped -> 8 b64 stores each (was 32 b16 each); Vt b16 scatter.
//  - P2 QK^T swapped (S^T = mfma(K-frag, Q-frag)); scale folded into exp2;
//    normalization deferred past PV. P: 8 b64. PV swapped: attn 2 b64.
//  - P3/P5 swapped: x1/G b64 stores; x residual + bias + out as float4.
// Barrier structure identical to v5 (9 barriers, barrier-free head loop on
// per-wave rows, FF ping-pong).
// MFMA 16x16x32 bf16. A-frag: A[m=lane&15][k=quad*8+j]; B-frag:
// B[k=quad*8+j][n=lane&15]; C/D: col=lane&15, row=quad*4+reg (learn_hip m89/m91).

typedef short bf16x8 __attribute__((ext_vector_type(8)));   // 8 bf16 in 4 VGPRs
typedef float f32x4  __attribute__((ext_vector_type(4)));
typedef unsigned short u16;
typedef unsigned int   u32;

#define TT   128
#define DDIM 128
#define FFD  512
#define PIT  136   // LDS row pitch (bf16): 272 B -> rows 16B-aligned

// SCALE * log2(e): softmax in exp2 domain. SCALE = 128^-0.5 (full embed dim).
#define QSC 0.12751744f

#if defined(__has_builtin)
#if __has_builtin(__builtin_amdgcn_exp2f)
#define EXP2F(x) __builtin_amdgcn_exp2f(x)
#else
#define EXP2F(x) exp2f(x)
#endif
#else
#define EXP2F(x) exp2f(x)
#endif

__device__ __forceinline__ u16 f2b(float f) {
    __hip_bfloat16 h = __float2bfloat16(f);   // RNE
    return __builtin_bit_cast(u16, h);
}
__device__ __forceinline__ u32 pk2(float x, float y) {
    return (u32)f2b(x) | ((u32)f2b(y) << 16);
}
__device__ __forceinline__ void st_b64(u16* p, u32 lo, u32 hi) {  // 8B-aligned
    uint2 v; v.x = lo; v.y = hi;
    *reinterpret_cast<uint2*>(p) = v;
}
__device__ __forceinline__ bf16x8 ldfrag(const u16* p) {  // LDS, 16B-aligned
    return __builtin_bit_cast(bf16x8, *reinterpret_cast<const uint4*>(p));
}
// Load 8 f32 from global, round to bf16 fragment (16B-aligned base).
__device__ __forceinline__ bf16x8 ldfrag_f32(const float* p) {
    float4 a = *reinterpret_cast<const float4*>(p);
    float4 b = *reinterpret_cast<const float4*>(p + 4);
    bf16x8 r;
    r[0] = (short)f2b(a.x); r[1] = (short)f2b(a.y);
    r[2] = (short)f2b(a.z); r[3] = (short)f2b(a.w);
    r[4] = (short)f2b(b.x); r[5] = (short)f2b(b.y);
    r[6] = (short)f2b(b.z); r[7] = (short)f2b(b.w);
    return r;
}
__device__ __forceinline__ f32x4 mfma16(bf16x8 a, bf16x8 b, f32x4 c) {
    return __builtin_amdgcn_mfma_f32_16x16x32_bf16(a, b, c, 0, 0, 0);
}

__global__ __launch_bounds__(512, 2) void tblock_kernel(
    const float* __restrict__ x,
    const float* __restrict__ ln1g, const float* __restrict__ ln1b,
    const float* __restrict__ Wq,   const float* __restrict__ Wk, const float* __restrict__ Wv,
    const float* __restrict__ Wo,   const float* __restrict__ bo,
    const float* __restrict__ ln2g, const float* __restrict__ ln2b,
    const float* __restrict__ W1,   const float* __restrict__ b1,
    const float* __restrict__ W2,   const float* __restrict__ b2,
    float* __restrict__ out)
{
    __shared__ __align__(16) u16 sm[4 * TT * PIT];
    u16* bufA = sm;                   // hs(LN1) -> P (per-wave rows) -> G (fc even)
    u16* bufB = sm + 1 * TT * PIT;    // Q -> attn (per-wave rows) -> G (fc odd)
    u16* bufC = sm + 2 * TT * PIT;    // K -> x1 (bf16 for LN2)
    u16* bufD = sm + 3 * TT * PIT;    // Vt -> h2 (LN2)

    const int b    = blockIdx.x;
    const int tid  = threadIdx.x;
    const int w    = tid >> 6;     // wave id 0..7
    const int l    = tid & 63;
    const int lq   = l & 15;
    const int quad = l >> 4;
    const float* xb = x + (size_t)b * (TT * DDIM);

    // ---------------- P0: LN1(x) -> bufA (bf16) ----------------
    {
        const int row = tid >> 2, part = tid & 3;
        const float* src = xb + row * DDIM + part * 32;
        float v[32];
        float s = 0.f, s2 = 0.f;
        #pragma unroll
        for (int i = 0; i < 8; i++) {
            float4 u = *reinterpret_cast<const float4*>(src + i * 4);
            v[i * 4 + 0] = u.x; v[i * 4 + 1] = u.y;
            v[i * 4 + 2] = u.z; v[i * 4 + 3] = u.w;
            s  += u.x + u.y + u.z + u.w;
            s2 += u.x * u.x + u.y * u.y + u.z * u.z + u.w * u.w;
        }
        s  += __shfl_xor(s, 1);  s2 += __shfl_xor(s2, 1);
        s  += __shfl_xor(s, 2);  s2 += __shfl_xor(s2, 2);
        float mean = s * (1.f / 128.f);
        float var  = fmaxf(s2 * (1.f / 128.f) - mean * mean, 0.f);
        float rstd = rsqrtf(var + 1e-5f);
        u16* dst = bufA + row * PIT + part * 32;
        #pragma unroll
        for (int i = 0; i < 4; i++) {
            u32 o4[4];
            #pragma unroll
            for (int j = 0; j < 4; j++) {
                int c = part * 32 + i * 8 + 2 * j;
                float r0 = (v[i * 8 + 2 * j]     - mean) * rstd * ln1g[c]     + ln1b[c];
                float r1 = (v[i * 8 + 2 * j + 1] - mean) * rstd * ln1g[c + 1] + ln1b[c + 1];
                o4[j] = (u32)f2b(r0) | ((u32)f2b(r1) << 16);
            }
            uint4 pk; pk.x = o4[0]; pk.y = o4[1]; pk.z = o4[2]; pk.w = o4[3];
            *reinterpret_cast<uint4*>(dst + i * 8) = pk;
        }
    }
    __syncthreads();

    // ---------------- P1: Q -> bufB, K -> bufC (swapped, b64); Vt -> bufD ----
    {
        // Swapped Q/K: A = W rows (wave's 16 out-dims), B = hs rows (t-tiles).
        // Lane gets (dout = w*16+quad*4+r, t = m*16+lq) -> b64 row-major store.
        bf16x8 aq[4], ak[4];
        #pragma unroll
        for (int ks = 0; ks < 4; ks++) {
            aq[ks] = ldfrag_f32(Wq + (w * 16 + lq) * DDIM + ks * 32 + quad * 8);
            ak[ks] = ldfrag_f32(Wk + (w * 16 + lq) * DDIM + ks * 32 + quad * 8);
        }
        #pragma unroll
        for (int m = 0; m < 8; m++) {
            f32x4 accq = {0, 0, 0, 0}, acck = {0, 0, 0, 0};
            #pragma unroll
            for (int ks = 0; ks < 4; ks++) {
                bf16x8 bh = ldfrag(bufA + (m * 16 + lq) * PIT + ks * 32 + quad * 8);
                accq = mfma16(aq[ks], bh, accq);
                acck = mfma16(ak[ks], bh, acck);
            }
            int t = m * 16 + lq;
            st_b64(bufB + t * PIT + w * 16 + quad * 4, pk2(accq[0], accq[1]), pk2(accq[2], accq[3]));
            st_b64(bufC + t * PIT + w * 16 + quad * 4, pk2(acck[0], acck[1]), pk2(acck[2], acck[3]));
        }
        // Vt = Wv @ hs^T (A = Wv rows, B = hs rows): lane gets (o=w16+quad*4+r,
        // t=n*16+lq) -> [o][t] store is cross-row: b16 scatter (unavoidable).
        bf16x8 av[4];
        #pragma unroll
        for (int ks = 0; ks < 4; ks++)
            av[ks] = ldfrag_f32(Wv + (w * 16 + lq) * DDIM + ks * 32 + quad * 8);
        #pragma unroll
        for (int n = 0; n < 8; n++) {
            f32x4 acc = {0, 0, 0, 0};
            #pragma unroll
            for (int ks = 0; ks < 4; ks++) {
                bf16x8 bh = ldfrag(bufA + (n * 16 + lq) * PIT + ks * 32 + quad * 8);
                acc = mfma16(av[ks], bh, acc);
            }
            #pragma unroll
            for (int r = 0; r < 4; r++) {
                int o = w * 16 + quad * 4 + r;
                bufD[o * PIT + n * 16 + lq] = f2b(acc[r]);
            }
        }
    }
    __syncthreads();

    // ---------------- P2: attention, barrier-free (per-wave rows) ----------
    // Swapped S^T = mfma(K-frag, Q-frag): lane (lq,quad) holds the QUARTER of
    // score row t = w*16+lq at s = n*16+quad*4+r; full row spans the 4 lanes
    // with equal lq -> softmax reduce = 2 cross-quad butterflies.
    const int trow = w * 16 + lq;
    #pragma unroll 1
    for (int h = 0; h < 4; h++) {
        // Q B-frag for this head (k = head's 32 dims)
        bf16x8 qb = ldfrag(bufB + trow * PIT + h * 32 + quad * 8);
        float p[8][4];
        #pragma unroll
        for (int n = 0; n < 8; n++) {
            bf16x8 ka = ldfrag(bufC + (n * 16 + lq) * PIT + h * 32 + quad * 8);
            f32x4 s4 = mfma16(ka, qb, f32x4{0, 0, 0, 0});
            #pragma unroll
            for (int r = 0; r < 4; r++) p[n][r] = s4[r];
        }
        // causal softmax (exp2 domain, scale folded, norm deferred):
        // quarter-row local max/sum, then cross-quad reduce (lanes lq+16k).
        float mx = -3.0e38f;
        #pragma unroll
        for (int n = 0; n < 8; n++) {
            #pragma unroll
            for (int r = 0; r < 4; r++) {
                int sc = n * 16 + quad * 4 + r;
                float q = p[n][r] * QSC;
                p[n][r] = q;
                mx = (sc <= trow) ? fmaxf(mx, q) : mx;
            }
        }
        mx = fmaxf(mx, __shfl_xor(mx, 16));
        mx = fmaxf(mx, __shfl_xor(mx, 32));   // full-row max
        float sum = 0.f;
        #pragma unroll
        for (int n = 0; n < 8; n++) {
            float e[4];
            #pragma unroll
            for (int r = 0; r < 4; r++) {
                int sc = n * 16 + quad * 4 + r;
                e[r] = (sc <= trow) ? EXP2F(p[n][r] - mx) : 0.f;
                sum += e[r];
            }
            st_b64(bufA + trow * PIT + n * 16 + quad * 4, pk2(e[0], e[1]), pk2(e[2], e[3]));
        }
        sum += __shfl_xor(sum, 16);
        sum += __shfl_xor(sum, 32);           // full-row sum
        float inv = 1.f / sum;   // sum >= 1 (max entry contributes exp2(0)=1)
        // own-row P stores must land before own PV reads (rule #18 fence)
        asm volatile("s_waitcnt lgkmcnt(0)" ::: "memory");
        __builtin_amdgcn_sched_barrier(0);
        // Swapped PV: attn^T = mfma(A=Vt, B=P); PV output rows are n=lq = trow
        // -> lane's inv applies directly; store attn[t][o] as b64.
        f32x4 o0 = {0, 0, 0, 0}, o1 = {0, 0, 0, 0};
        #pragma unroll
        for (int ks = 0; ks < 4; ks++) {
            bf16x8 pb  = ldfrag(bufA + trow * PIT + ks * 32 + quad * 8);
            bf16x8 va0 = ldfrag(bufD + (h * 32 + lq) * PIT + ks * 32 + quad * 8);
            bf16x8 va1 = ldfrag(bufD + (h * 32 + 16 + lq) * PIT + ks * 32 + quad * 8);
            o0 = mfma16(va0, pb, o0);
            o1 = mfma16(va1, pb, o1);
        }
        #pragma unroll
        for (int r = 0; r < 4; r++) { o0[r] *= inv; o1[r] *= inv; }
        st_b64(bufB + trow * PIT + h * 32 + quad * 4,      pk2(o0[0], o0[1]), pk2(o0[2], o0[3]));
        st_b64(bufB + trow * PIT + h * 32 + 16 + quad * 4, pk2(o1[0], o1[1]), pk2(o1[2], o1[3]));
    }
    __syncthreads();   // attn concat complete across all waves

    // ---------------- P3: x1 = x + attn @ Wo^T + bo (swapped) --------------
    // Lane holds x1[t = m*16+lq][d = w*16+quad*4+r]: float4 residual/bias,
    // b64 store to bufC, f32 regs for P6.
    float x1res[8][4];
    {
        bf16x8 woa[4];
        #pragma unroll
        for (int ks = 0; ks < 4; ks++)
            woa[ks] = ldfrag_f32(Wo + (w * 16 + lq) * DDIM + ks * 32 + quad * 8);
        const float4 bo4 = *reinterpret_cast<const float4*>(bo + w * 16 + quad * 4);
        #pragma unroll
        for (int m = 0; m < 8; m++) {
            f32x4 acc = {0, 0, 0, 0};
            #pragma unroll
            for (int ks = 0; ks < 4; ks++) {
                bf16x8 ab = ldfrag(bufB + (m * 16 + lq) * PIT + ks * 32 + quad * 8);
                acc = mfma16(woa[ks], ab, acc);
            }
            int t = m * 16 + lq;
            const float4 xv = *reinterpret_cast<const float4*>(xb + t * DDIM + w * 16 + quad * 4);
            float v0 = acc[0] + xv.x + bo4.x;
            float v1 = acc[1] + xv.y + bo4.y;
            float v2 = acc[2] + xv.z + bo4.z;
            float v3 = acc[3] + xv.w + bo4.w;
            x1res[m][0] = v0; x1res[m][1] = v1; x1res[m][2] = v2; x1res[m][3] = v3;
            st_b64(bufC + t * PIT + w * 16 + quad * 4, pk2(v0, v1), pk2(v2, v3));
        }
    }
    __syncthreads();

    // ---------------- P4: LN2(x1) -> bufD (bf16) ----------------
    {
        const int row = tid >> 2, part = tid & 3;
        const u16* src = bufC + row * PIT + part * 32;
        float v[32];
        float s = 0.f, s2 = 0.f;
        #pragma unroll
        for (int i = 0; i < 4; i++) {
            uint4 u = *reinterpret_cast<const uint4*>(src + i * 8);
            u32 arr[4] = {u.x, u.y, u.z, u.w};
            #pragma unroll
            for (int j = 0; j < 4; j++) {
                float f0 = __uint_as_float((arr[j] & 0xffffu) << 16);
                float f1 = __uint_as_float(arr[j] & 0xffff0000u);
                v[i * 8 + 2 * j] = f0; v[i * 8 + 2 * j + 1] = f1;
                s += f0 + f1; s2 += f0 * f0 + f1 * f1;
            }
        }
        s  += __shfl_xor(s, 1);  s2 += __shfl_xor(s2, 1);
        s  += __shfl_xor(s, 2);  s2 += __shfl_xor(s2, 2);
        float mean = s * (1.f / 128.f);
        float var  = fmaxf(s2 * (1.f / 128.f) - mean * mean, 0.f);
        float rstd = rsqrtf(var + 1e-5f);
        u16* dst = bufD + row * PIT + part * 32;
        #pragma unroll
        for (int i = 0; i < 4; i++) {
            u32 o4[4];
            #pragma unroll
            for (int j = 0; j < 4; j++) {
                int c = part * 32 + i * 8 + 2 * j;
                float r0 = (v[i * 8 + 2 * j]     - mean) * rstd * ln2g[c]     + ln2b[c];
                float r1 = (v[i * 8 + 2 * j + 1] - mean) * rstd * ln2g[c + 1] + ln2b[c + 1];
                o4[j] = (u32)f2b(r0) | ((u32)f2b(r1) << 16);
            }
            uint4 pk; pk.x = o4[0]; pk.y = o4[1]; pk.z = o4[2]; pk.w = o4[3];
            *reinterpret_cast<uint4*>(dst + i * 8) = pk;
        }
    }
    __syncthreads();

    // ---------------- P5: FF (swapped); G ping-pongs A/B -------------------
    f32x4 oacc[8];
    #pragma unroll
    for (int m = 0; m < 8; m++) oacc[m] = f32x4{0, 0, 0, 0};

    #pragma unroll 1
    for (int fc = 0; fc < 4; fc++) {
        const int fbase = fc * 128;
        u16* gbuf = (fc & 1) ? bufB : bufA;   // both dead after P3; WAR-free swap
        // G = relu(h2 @ W1c^T + b1): lane gets (f = w16+quad*4+r, t = m16+lq)
        bf16x8 w1a[4];
        #pragma unroll
        for (int ks = 0; ks < 4; ks++)
            w1a[ks] = ldfrag_f32(W1 + (fbase + w * 16 + lq) * DDIM + ks * 32 + quad * 8);
        const float4 b14 = *reinterpret_cast<const float4*>(b1 + fbase + w * 16 + quad * 4);
        #pragma unroll
        for (int m = 0; m < 8; m++) {
            f32x4 acc = {0, 0, 0, 0};
            #pragma unroll
            for (int ks = 0; ks < 4; ks++) {
                bf16x8 hb = ldfrag(bufD + (m * 16 + lq) * PIT + ks * 32 + quad * 8);
                acc = mfma16(w1a[ks], hb, acc);
            }
            int t = m * 16 + lq;
            float g0 = fmaxf(acc[0] + b14.x, 0.f);
            float g1 = fmaxf(acc[1] + b14.y, 0.f);
            float g2 = fmaxf(acc[2] + b14.z, 0.f);
            float g3 = fmaxf(acc[3] + b14.w, 0.f);
            st_b64(gbuf + t * PIT + w * 16 + quad * 4, pk2(g0, g1), pk2(g2, g3));
        }
        __syncthreads();   // G_fc complete (cross-wave read follows)
        // oacc^T += W2c @ G^T: lane accumulates (d = w16+quad*4+r, t = m16+lq)
        bf16x8 w2a[4];
        #pragma unroll
        for (int ks = 0; ks < 4; ks++)
            w2a[ks] = ldfrag_f32(W2 + (w * 16 + lq) * FFD + fbase + ks * 32 + quad * 8);
        #pragma unroll
        for (int m = 0; m < 8; m++) {
            #pragma unroll
            for (int ks = 0; ks < 4; ks++) {
                bf16x8 gb = ldfrag(gbuf + (m * 16 + lq) * PIT + ks * 32 + quad * 8);
                oacc[m] = mfma16(w2a[ks], gb, oacc[m]);
            }
        }
        // no trailing barrier: next fc writes the OTHER buffer
    }

    // ---------------- P6: out = x1 + ff + b2 (float4 stores) ---------------
    {
        const float4 b24 = *reinterpret_cast<const float4*>(b2 + w * 16 + quad * 4);
        float* ob = out + (size_t)b * (TT * DDIM);
        #pragma unroll
        for (int m = 0; m < 8; m++) {
            int t = m * 16 + lq;
            float4 o;
            o.x = oacc[m][0] + x1res[m][0] + b24.x;
            o.y = oacc[m][1] + x1res[m][1] + b24.y;
            o.z = oacc[m][2] + x1res[m][2] + b24.z;
            o.w = oacc[m][3] + x1res[m][3] + b24.w;
            *reinterpret_cast<float4*>(ob + t * DDIM + w * 16 + quad * 4) = o;
        }
    }
}

extern "C" void kernel_launch(void* const* d_in, const int* in_sizes, int n_in,
                              void* d_out, int out_size, void* d_ws, size_t ws_size,
                              hipStream_t stream) {
    const float* x    = (const float*)d_in[0];
    const float* ln1g = (const float*)d_in[1];
    const float* ln1b = (const float*)d_in[2];
    const float* Wq   = (const float*)d_in[3];
    const float* Wk   = (const float*)d_in[4];
    const float* Wv   = (const float*)d_in[5];
    const float* Wo   = (const float*)d_in[6];
    const float* bo   = (const float*)d_in[7];
    const float* ln2g = (const float*)d_in[8];
    const float* ln2b = (const float*)d_in[9];
    const float* W1   = (const float*)d_in[10];
    const float* b1   = (const float*)d_in[11];
    const float* W2   = (const float*)d_in[12];
    const float* b2   = (const float*)d_in[13];
    float* out = (float*)d_out;

    const int nblocks = in_sizes[0] / (TT * DDIM);   // B = 1024
    tblock_kernel<<<dim3(nblocks), dim3(512), 0, stream>>>(
        x, ln1g, ln1b, Wq, Wk, Wv, Wo, bo, ln2g, ln2b, W1, b1, W2, b2, out);
}